// Round 1
// baseline (1532.481 us; speedup 1.0000x reference)
//
#include <hip/hip_runtime.h>
#include <hip/hip_bf16.h>

#define M_DIM 8192
#define N_DIM 16384
#define K_DIM 4096
#define BM 128
#define BN 128
#define BK 32

typedef __attribute__((ext_vector_type(8))) short short8;
typedef __attribute__((ext_vector_type(4))) float floatx4;
typedef __attribute__((ext_vector_type(4))) int intx4;

__device__ __forceinline__ unsigned short f32_to_bf16(float f) {
  unsigned int u = __float_as_uint(f);
  unsigned int r = (u + 0x7fffu + ((u >> 16) & 1u)) >> 16;
  return (unsigned short)r;
}

__device__ __forceinline__ void gload_lds16(const void* g, void* l) {
  __builtin_amdgcn_global_load_lds(
      (const __attribute__((address_space(1))) unsigned int*)g,
      (__attribute__((address_space(3))) unsigned int*)l, 16, 0, 0);
}

// W[n][k] int32 in [0,255]  ->  bf16 (q - zp), exact integers in bf16
__global__ __launch_bounds__(256) void convert_w_kernel(
    const int* __restrict__ q, const float* __restrict__ zpp,
    unsigned short* __restrict__ wb) {
  const float zp = *zpp;
  size_t t = (size_t)blockIdx.x * 256 + threadIdx.x;
  const int* src = q + t * 8;
  intx4 q0 = *(const intx4*)(src);
  intx4 q1 = *(const intx4*)(src + 4);
  union { short8 v; unsigned short u[8]; } r;
#pragma unroll
  for (int j = 0; j < 4; ++j) {
    r.u[j]     = f32_to_bf16((float)q0[j] - zp);
    r.u[4 + j] = f32_to_bf16((float)q1[j] - zp);
  }
  *(short8*)(wb + t * 8) = r.v;
}

// x fp32 -> bf16 (RNE)
__global__ __launch_bounds__(256) void convert_x_kernel(
    const float* __restrict__ x, unsigned short* __restrict__ xb) {
  size_t t = (size_t)blockIdx.x * 256 + threadIdx.x;
  const float* src = x + t * 8;
  floatx4 x0 = *(const floatx4*)(src);
  floatx4 x1 = *(const floatx4*)(src + 4);
  union { short8 v; unsigned short u[8]; } r;
#pragma unroll
  for (int j = 0; j < 4; ++j) {
    r.u[j]     = f32_to_bf16(x0[j]);
    r.u[4 + j] = f32_to_bf16(x1[j]);
  }
  *(short8*)(xb + t * 8) = r.v;
}

// C[m][n] = scale * sum_k A[m][k]*B[n][k] + bias[n]
// A: [M][K] bf16, B: [N][K] bf16 (both K-major), m97 structure:
// 128x128 tile, BK=32, 4 waves (2x2), 16x16x32 MFMA, global_load_lds w=16.
__global__ __launch_bounds__(256) void gemm_bt_kernel(
    const unsigned short* __restrict__ A, const unsigned short* __restrict__ B,
    float* __restrict__ C, const float* __restrict__ scale_p,
    const float* __restrict__ bias) {
  __shared__ unsigned short As[BM * BK];  // [128][32] linear (global_load_lds needs linear)
  __shared__ unsigned short Bs[BN * BK];

  const int NBN = N_DIM / BN;                       // 128
  const int NWG = (M_DIM / BM) * NBN;               // 8192, % 8 == 0
  int bid = blockIdx.x;
  int swz = (bid & 7) * (NWG / 8) + (bid >> 3);     // XCD-aware swizzle (bijective)
  int bm = swz / NBN;
  int bn = swz % NBN;

  int tid = threadIdx.x;
  int wave = tid >> 6;
  int lane = tid & 63;
  int wr = wave >> 1, wc = wave & 1;

  // staging address components (constant across K loop except k0)
  int srow = (lane >> 2);          // 0..15 within 16-row chunk
  int scol = (lane & 3) * 8;       // 0,8,16,24
  const unsigned short* gA0 = A + (size_t)(bm * BM) * K_DIM;
  const unsigned short* gB0 = B + (size_t)(bn * BN) * K_DIM;

  floatx4 acc[4][4] = {};

  for (int kt = 0; kt < K_DIM / BK; ++kt) {
    int k0 = kt * BK;
    // stage: 8 chunks of 16 rows each for A and B; wave w does chunks w, w+4
#pragma unroll
    for (int i = 0; i < 2; ++i) {
      int chunk = i * 4 + wave;              // 0..7
      int row = chunk * 16 + srow;
      const unsigned short* ga = gA0 + (size_t)row * K_DIM + k0 + scol;
      gload_lds16(ga, As + chunk * 512);
      const unsigned short* gb = gB0 + (size_t)row * K_DIM + k0 + scol;
      gload_lds16(gb, Bs + chunk * 512);
    }
    __syncthreads();  // vmcnt drain + barrier: tile ready

    short8 af[4], bf[4];
    int fr = lane & 15;
    int kk = (lane >> 4) * 8;
#pragma unroll
    for (int mi = 0; mi < 4; ++mi) {
      int r = wr * 64 + mi * 16 + fr;
      af[mi] = *(const short8*)(As + r * BK + kk);
    }
#pragma unroll
    for (int ni = 0; ni < 4; ++ni) {
      int r = wc * 64 + ni * 16 + fr;
      bf[ni] = *(const short8*)(Bs + r * BK + kk);
    }
#pragma unroll
    for (int mi = 0; mi < 4; ++mi)
#pragma unroll
      for (int ni = 0; ni < 4; ++ni)
        acc[mi][ni] = __builtin_amdgcn_mfma_f32_16x16x32_bf16(
            af[mi], bf[ni], acc[mi][ni], 0, 0, 0);
    __syncthreads();  // reads done before next stage overwrites
  }

  // epilogue: C/D layout col=lane&15, row=(lane>>4)*4+reg  [m89]
  float s = *scale_p;
  int rowbase = bm * BM + wr * 64 + (lane >> 4) * 4;
  int colbase = bn * BN + wc * 64 + (lane & 15);
#pragma unroll
  for (int ni = 0; ni < 4; ++ni) {
    int col = colbase + ni * 16;
    float bv = bias[col];
#pragma unroll
    for (int mi = 0; mi < 4; ++mi) {
#pragma unroll
      for (int r = 0; r < 4; ++r) {
        int row = rowbase + mi * 16 + r;
        C[(size_t)row * N_DIM + col] = s * acc[mi][ni][r] + bv;
      }
    }
  }
}

// correctness fallback if ws too small (slow, should not normally run)
__global__ __launch_bounds__(256) void naive_kernel(
    const float* __restrict__ x, const int* __restrict__ q,
    const float* __restrict__ sp, const float* __restrict__ zpp,
    const float* __restrict__ bias, float* __restrict__ out) {
  float s = *sp, zp = *zpp;
  size_t total = (size_t)M_DIM * N_DIM;
  size_t stride = (size_t)gridDim.x * blockDim.x;
  for (size_t t = (size_t)blockIdx.x * blockDim.x + threadIdx.x; t < total;
       t += stride) {
    size_t m = t / N_DIM, n = t % N_DIM;
    const float* xr = x + m * K_DIM;
    const int* qr = q + n * K_DIM;
    float acc = 0.f;
    for (int k = 0; k < K_DIM; ++k) acc += xr[k] * ((float)qr[k] - zp);
    out[t] = s * acc + bias[n];
  }
}

extern "C" void kernel_launch(void* const* d_in, const int* in_sizes, int n_in,
                              void* d_out, int out_size, void* d_ws,
                              size_t ws_size, hipStream_t stream) {
  const float* x = (const float*)d_in[0];
  const int* qw = (const int*)d_in[1];
  const float* scale = (const float*)d_in[2];
  const float* zp = (const float*)d_in[3];
  const float* bias = (const float*)d_in[4];
  float* out = (float*)d_out;

  const size_t needW = (size_t)N_DIM * K_DIM * sizeof(unsigned short);  // 128 MiB
  const size_t needX = (size_t)M_DIM * K_DIM * sizeof(unsigned short);  //  64 MiB

  if (ws_size >= needW + needX) {
    unsigned short* wb = (unsigned short*)d_ws;
    unsigned short* xb = (unsigned short*)((char*)d_ws + needW);
    convert_w_kernel<<<(unsigned)((size_t)N_DIM * K_DIM / 2048), 256, 0, stream>>>(qw, zp, wb);
    convert_x_kernel<<<(unsigned)((size_t)M_DIM * K_DIM / 2048), 256, 0, stream>>>(x, xb);
    gemm_bt_kernel<<<(M_DIM / BM) * (N_DIM / BN), 256, 0, stream>>>(xb, wb, out, scale, bias);
  } else {
    naive_kernel<<<4096, 256, 0, stream>>>(x, qw, scale, zp, bias, out);
  }
}

// Round 2
// 1520.568 us; speedup vs baseline: 1.0078x; 1.0078x over previous
//
#include <hip/hip_runtime.h>
#include <hip/hip_bf16.h>

#define M_DIM 8192
#define N_DIM 16384
#define K_DIM 4096
#define BM 256
#define BN 256
#define BK 32
#define NKT (K_DIM / BK)   // 128 K-tiles

typedef __attribute__((ext_vector_type(8))) short short8;
typedef __attribute__((ext_vector_type(4))) float floatx4;
typedef __attribute__((ext_vector_type(4))) int intx4;

__device__ __forceinline__ unsigned short f32_to_bf16(float f) {
  unsigned int u = __float_as_uint(f);
  unsigned int r = (u + 0x7fffu + ((u >> 16) & 1u)) >> 16;
  return (unsigned short)r;
}

__device__ __forceinline__ void gload_lds16(const void* g, void* l) {
  __builtin_amdgcn_global_load_lds(
      (const __attribute__((address_space(1))) unsigned int*)g,
      (__attribute__((address_space(3))) unsigned int*)l, 16, 0, 0);
}

__device__ __forceinline__ floatx4 mfma16(short8 a, short8 b, floatx4 c) {
  return __builtin_amdgcn_mfma_f32_16x16x32_bf16(a, b, c, 0, 0, 0);
}

// W[n][k] int32 in [0,255] -> bf16 (q - zp), exact integers in bf16
__global__ __launch_bounds__(256) void convert_w_kernel(
    const int* __restrict__ q, const float* __restrict__ zpp,
    unsigned short* __restrict__ wb) {
  const float zp = *zpp;
  size_t t = (size_t)blockIdx.x * 256 + threadIdx.x;
  const int* src = q + t * 8;
  intx4 q0 = *(const intx4*)(src);
  intx4 q1 = *(const intx4*)(src + 4);
  union { short8 v; unsigned short u[8]; } r;
#pragma unroll
  for (int j = 0; j < 4; ++j) {
    r.u[j]     = f32_to_bf16((float)q0[j] - zp);
    r.u[4 + j] = f32_to_bf16((float)q1[j] - zp);
  }
  *(short8*)(wb + t * 8) = r.v;
}

// x fp32 -> bf16 (RNE)
__global__ __launch_bounds__(256) void convert_x_kernel(
    const float* __restrict__ x, unsigned short* __restrict__ xb) {
  size_t t = (size_t)blockIdx.x * 256 + threadIdx.x;
  const float* src = x + t * 8;
  floatx4 x0 = *(const floatx4*)(src);
  floatx4 x1 = *(const floatx4*)(src + 4);
  union { short8 v; unsigned short u[8]; } r;
#pragma unroll
  for (int j = 0; j < 4; ++j) {
    r.u[j]     = f32_to_bf16(x0[j]);
    r.u[4 + j] = f32_to_bf16(x1[j]);
  }
  *(short8*)(xb + t * 8) = r.v;
}

// C[m][n] = scale * sum_k A[m][k]*B[n][k] + bias[n]
// 256x256 tile, BK=32, 8 waves (2Mx4N), 4-deep LDS ring, counted vmcnt,
// raw s_barrier 2-phase schedule, LDS slot-XOR swizzle (T1+T2+T3+T4+T5).
__global__ __launch_bounds__(512, 2) void gemm_bt_kernel(
    const unsigned short* __restrict__ A, const unsigned short* __restrict__ B,
    float* __restrict__ C, const float* __restrict__ scale_p,
    const float* __restrict__ bias) {
  __shared__ unsigned short As[4][BM * BK];  // 4 x 16 KiB
  __shared__ unsigned short Bs[4][BN * BK];  // 4 x 16 KiB  (total 128 KiB)

  const int NBM = M_DIM / BM;                // 32
  const int NBN = N_DIM / BN;                // 64
  const int NWG = NBM * NBN;                 // 2048, % 8 == 0
  int bid = blockIdx.x;
  int swz = (bid & 7) * (NWG / 8) + (bid >> 3);  // XCD-aware, bijective
  int bm = swz & 31;                             // consecutive swz share bn (B panel in L2)
  int bn = swz >> 5;

  int tid = threadIdx.x;
  int wave = tid >> 6, lane = tid & 63;
  int wr = wave >> 2, wc = wave & 3;         // 2 x 4 wave grid

  // ---- staging geometry (pre-swizzled global source, linear LDS dest) ----
  // wave stages chunks 2w,2w+1 (16 rows x 64B each) of both A and B tiles.
  // LDS linear: chunk c, lane l -> row c*16 + (l>>2), 16B-slot (l&3).
  // swizzle: lds slot s holds global slot s ^ ((row>>1)&3) = s ^ ((l>>3)&3).
  int s_r = lane >> 2;
  int s_slot = (lane & 3) ^ ((lane >> 3) & 3);
  const unsigned short* gA = A + (size_t)(bm * BM + wave * 32 + s_r) * K_DIM + s_slot * 8;
  const unsigned short* gB = B + (size_t)(bn * BN + wave * 32 + s_r) * K_DIM + s_slot * 8;
  const size_t gstep = (size_t)16 * K_DIM;   // chunk-to-chunk row step
  int ldst = (wave * 2) * 512;               // lds short-offset of first chunk

  // ---- read geometry ----
  // fragment: row = base + fr, k-slot ks; swizzled slot = ks ^ ((row>>1)&3)
  // (row>>1)&3 == (fr>>1)&3 because all row bases are multiples of 8.
  int fr = lane & 15;
  int ks = lane >> 4;
  int swk = ks ^ ((fr >> 1) & 3);
  int aoff = (wr * 128 + fr) * BK + swk * 8; // short offset; +mi*512, +2048 for hi half
  int boff = (wc * 64 + fr) * BK + swk * 8;  // +ni*512

  floatx4 acc[8][4] = {};

  // ---- prologue: stage K-tiles 0,1,2 (12 loads/wave) ----
  for (int u = 0; u < 3; ++u) {
#pragma unroll
    for (int i = 0; i < 2; ++i) {
      gload_lds16(gA + (size_t)i * gstep + u * BK, &As[u][ldst + i * 512]);
      gload_lds16(gB + (size_t)i * gstep + u * BK, &Bs[u][ldst + i * 512]);
    }
  }
  asm volatile("s_waitcnt vmcnt(8)" ::: "memory");  // K-tile 0 landed
  __builtin_amdgcn_s_barrier();

  for (int t = 0; t < NKT; ++t) {
    const unsigned short* Ab = As[t & 3];
    const unsigned short* Bb = Bs[t & 3];
    int u = t + 3;
    // ======== phase A: mi 0..3 ========
    short8 a0[4], b0[4];
#pragma unroll
    for (int mi = 0; mi < 4; ++mi)
      a0[mi] = *(const short8*)(Ab + aoff + mi * 512);
#pragma unroll
    for (int ni = 0; ni < 4; ++ni)
      b0[ni] = *(const short8*)(Bb + boff + ni * 512);
    if (u < NKT) {
#pragma unroll
      for (int i = 0; i < 2; ++i)
        gload_lds16(gA + (size_t)i * gstep + u * BK, &As[u & 3][ldst + i * 512]);
    }
    __builtin_amdgcn_s_barrier();
    __builtin_amdgcn_s_setprio(1);
#pragma unroll
    for (int mi = 0; mi < 4; ++mi)
#pragma unroll
      for (int ni = 0; ni < 4; ++ni)
        acc[mi][ni] = mfma16(a0[mi], b0[ni], acc[mi][ni]);
    __builtin_amdgcn_s_setprio(0);
    __builtin_amdgcn_s_barrier();
    // ======== phase B: mi 4..7 ========
    short8 a1[4];
#pragma unroll
    for (int mi = 0; mi < 4; ++mi)
      a1[mi] = *(const short8*)(Ab + aoff + 2048 + mi * 512);
    if (u < NKT) {
#pragma unroll
      for (int i = 0; i < 2; ++i)
        gload_lds16(gB + (size_t)i * gstep + u * BK, &Bs[u & 3][ldst + i * 512]);
    }
    // counted vmcnt, once per K-tile: keep tiles t+2,t+3 (8 loads) in flight,
    // guarantee tile t+1 (oldest 4) has landed before next phase-A reads.
    if (t <= NKT - 4) { asm volatile("s_waitcnt vmcnt(8)" ::: "memory"); }
    else if (t == NKT - 3) { asm volatile("s_waitcnt vmcnt(4)" ::: "memory"); }
    else if (t == NKT - 2) { asm volatile("s_waitcnt vmcnt(0)" ::: "memory"); }
    __builtin_amdgcn_s_barrier();
    __builtin_amdgcn_s_setprio(1);
#pragma unroll
    for (int mi = 0; mi < 4; ++mi)
#pragma unroll
      for (int ni = 0; ni < 4; ++ni)
        acc[4 + mi][ni] = mfma16(a1[mi], b0[ni], acc[4 + mi][ni]);
    __builtin_amdgcn_s_setprio(0);
    __builtin_amdgcn_s_barrier();
  }

  // ---- epilogue: C/D layout col=lane&15, row=(lane>>4)*4+reg ----
  float s = *scale_p;
  int rowbase = bm * BM + wr * 128 + (lane >> 4) * 4;
  int colbase = bn * BN + wc * 64 + (lane & 15);
#pragma unroll
  for (int ni = 0; ni < 4; ++ni) {
    int col = colbase + ni * 16;
    float bv = bias[col];
#pragma unroll
    for (int mi = 0; mi < 8; ++mi) {
#pragma unroll
      for (int r = 0; r < 4; ++r) {
        int row = rowbase + mi * 16 + r;
        C[(size_t)row * N_DIM + col] = s * acc[mi][ni][r] + bv;
      }
    }
  }
}

// correctness fallback if ws too small (slow, should not normally run)
__global__ __launch_bounds__(256) void naive_kernel(
    const float* __restrict__ x, const int* __restrict__ q,
    const float* __restrict__ sp, const float* __restrict__ zpp,
    const float* __restrict__ bias, float* __restrict__ out) {
  float s = *sp, zp = *zpp;
  size_t total = (size_t)M_DIM * N_DIM;
  size_t stride = (size_t)gridDim.x * blockDim.x;
  for (size_t t = (size_t)blockIdx.x * blockDim.x + threadIdx.x; t < total;
       t += stride) {
    size_t m = t / N_DIM, n = t % N_DIM;
    const float* xr = x + m * K_DIM;
    const int* qr = q + n * K_DIM;
    float acc = 0.f;
    for (int k = 0; k < K_DIM; ++k) acc += xr[k] * ((float)qr[k] - zp);
    out[t] = s * acc + bias[n];
  }
}

extern "C" void kernel_launch(void* const* d_in, const int* in_sizes, int n_in,
                              void* d_out, int out_size, void* d_ws,
                              size_t ws_size, hipStream_t stream) {
  const float* x = (const float*)d_in[0];
  const int* qw = (const int*)d_in[1];
  const float* scale = (const float*)d_in[2];
  const float* zp = (const float*)d_in[3];
  const float* bias = (const float*)d_in[4];
  float* out = (float*)d_out;

  const size_t needW = (size_t)N_DIM * K_DIM * sizeof(unsigned short);  // 128 MiB
  const size_t needX = (size_t)M_DIM * K_DIM * sizeof(unsigned short);  //  64 MiB

  if (ws_size >= needW + needX) {
    unsigned short* wb = (unsigned short*)d_ws;
    unsigned short* xb = (unsigned short*)((char*)d_ws + needW);
    convert_w_kernel<<<(unsigned)((size_t)N_DIM * K_DIM / 2048), 256, 0, stream>>>(qw, zp, wb);
    convert_x_kernel<<<(unsigned)((size_t)M_DIM * K_DIM / 2048), 256, 0, stream>>>(x, xb);
    gemm_bt_kernel<<<(M_DIM / BM) * (N_DIM / BN), 512, 0, stream>>>(xb, wb, out, scale, bias);
  } else {
    naive_kernel<<<4096, 256, 0, stream>>>(x, qw, scale, zp, bias, out);
  }
}

// Round 3
// 1434.725 us; speedup vs baseline: 1.0681x; 1.0598x over previous
//
#include <hip/hip_runtime.h>
#include <hip/hip_bf16.h>

#define M_DIM 8192
#define N_DIM 16384
#define K_DIM 4096
#define BM 256
#define BN 256
#define BKT 64              // K per K-tile
#define NT (K_DIM / BKT)    // 64 K-tiles

typedef __attribute__((ext_vector_type(8))) short short8;
typedef __attribute__((ext_vector_type(4))) float floatx4;
typedef __attribute__((ext_vector_type(4))) int intx4;

__device__ __forceinline__ unsigned short f32_to_bf16(float f) {
  unsigned int u = __float_as_uint(f);
  unsigned int r = (u + 0x7fffu + ((u >> 16) & 1u)) >> 16;
  return (unsigned short)r;
}

__device__ __forceinline__ void gload_lds16(const void* g, void* l) {
  __builtin_amdgcn_global_load_lds(
      (const __attribute__((address_space(1))) unsigned int*)g,
      (__attribute__((address_space(3))) unsigned int*)l, 16, 0, 0);
}

__device__ __forceinline__ floatx4 mfma16(short8 a, short8 b, floatx4 c) {
  return __builtin_amdgcn_mfma_f32_16x16x32_bf16(a, b, c, 0, 0, 0);
}

// W[n][k] int32 in [0,255] -> bf16 (q - zp), exact integers in bf16
__global__ __launch_bounds__(256) void convert_w_kernel(
    const int* __restrict__ q, const float* __restrict__ zpp,
    unsigned short* __restrict__ wb) {
  const float zp = *zpp;
  size_t t = (size_t)blockIdx.x * 256 + threadIdx.x;
  const int* src = q + t * 8;
  intx4 q0 = *(const intx4*)(src);
  intx4 q1 = *(const intx4*)(src + 4);
  union { short8 v; unsigned short u[8]; } r;
#pragma unroll
  for (int j = 0; j < 4; ++j) {
    r.u[j]     = f32_to_bf16((float)q0[j] - zp);
    r.u[4 + j] = f32_to_bf16((float)q1[j] - zp);
  }
  *(short8*)(wb + t * 8) = r.v;
}

// x fp32 -> bf16 (RNE)
__global__ __launch_bounds__(256) void convert_x_kernel(
    const float* __restrict__ x, unsigned short* __restrict__ xb) {
  size_t t = (size_t)blockIdx.x * 256 + threadIdx.x;
  const float* src = x + t * 8;
  floatx4 x0 = *(const floatx4*)(src);
  floatx4 x1 = *(const floatx4*)(src + 4);
  union { short8 v; unsigned short u[8]; } r;
#pragma unroll
  for (int j = 0; j < 4; ++j) {
    r.u[j]     = f32_to_bf16(x0[j]);
    r.u[4 + j] = f32_to_bf16(x1[j]);
  }
  *(short8*)(xb + t * 8) = r.v;
}

#define VMC4 asm volatile("s_waitcnt vmcnt(4)" ::: "memory")
#define VMC0 asm volatile("s_waitcnt vmcnt(0)" ::: "memory")
#define BAR  __builtin_amdgcn_s_barrier()

// C[m][n] = scale * sum_k A[m][k]*B[n][k] + bias[n]
// 256x256 tile, BK=64, 8 waves (2Mx4N), 2-slot dbuf, quadrant-phased schedule:
// per phase {ds_reads || 2 gload_lds -> barrier -> setprio+16 MFMA}, counted
// vmcnt(4) every phase, XOR-swizzled LDS (16B-slot ^ row&7), XCD swizzle.
__global__ __launch_bounds__(512, 2) void gemm_bt_kernel(
    const unsigned short* __restrict__ A, const unsigned short* __restrict__ B,
    float* __restrict__ C, const float* __restrict__ scale_p,
    const float* __restrict__ bias) {
  __shared__ unsigned short As[2][256][64];  // 64 KiB
  __shared__ unsigned short Bs[2][256][64];  // 64 KiB

  const int NBM = M_DIM / BM;                    // 32
  const int NBN = N_DIM / BN;                    // 64
  const int NWG = NBM * NBN;                     // 2048, % 8 == 0
  int bid = blockIdx.x;
  int swz = (bid & 7) * (NWG / 8) + (bid >> 3);  // XCD-aware, bijective
  int bm = swz & 31;                             // consecutive swz share bn
  int bn = swz >> 5;

  int tid = threadIdx.x;
  int wave = tid >> 6, lane = tid & 63;
  int wr = wave >> 2, wc = wave & 3;             // 2M x 4N wave grid

  // ---- staging geometry ----
  // Each gload: 8 rows x 128B, linear LDS dest; swizzle via pre-permuted
  // global source: lds (row, slot s) holds global slot s ^ (row&7).
  int l8 = lane >> 3, l7 = lane & 7;
  int ssw = l7 ^ l8;  // (l&7) ^ ((l>>3)&7)
  const unsigned short* gA = A + (size_t)(bm * 256 + l8) * K_DIM + ssw * 8;
  const unsigned short* gB = B + (size_t)(bn * 256 + l8) * K_DIM + ssw * 8;
  // per-wave 16-row stage shares:
  int aloR = (wave < 4) ? wave * 16 : 128 + (wave - 4) * 16;  // A rows {0-63,128-191}
  int ahiR = aloR + 64;                                       // A rows {64-127,192-255}
  int bloR = (wave >> 1) * 64 + (wave & 1) * 16;              // B rows {0-31,64-95,...}
  int bhiR = bloR + 32;

#define STAGE(gp, larr, sl, row0, kt)                                          \
  do {                                                                         \
    gload_lds16(gp + (size_t)(row0)*K_DIM + (size_t)(kt) * 64,                 \
                &larr[sl][row0][0]);                                           \
    gload_lds16(gp + (size_t)((row0) + 8) * K_DIM + (size_t)(kt) * 64,         \
                &larr[sl][(row0) + 8][0]);                                     \
  } while (0)

  // ---- read geometry ----
  int fr = lane & 15, ks = lane >> 4;
  int fsw0 = ks ^ (fr & 7);        // kk=0 swizzled 16B slot
  int fsw1 = (4 + ks) ^ (fr & 7);  // kk=1

#define AFRAG(sl, mi, kk) \
  (*(const short8*)&As[sl][wr * 128 + (mi)*16 + fr][((kk) ? fsw1 : fsw0) * 8])
#define BFRAG(sl, ni, kk) \
  (*(const short8*)&Bs[sl][wc * 64 + (ni)*16 + fr][((kk) ? fsw1 : fsw0) * 8])

  floatx4 acc[8][4] = {};

  // ---- prologue: kt0 all 4 halves + A-lo(kt1) ----
  STAGE(gA, As, 0, aloR, 0);
  STAGE(gB, Bs, 0, bloR, 0);
  STAGE(gB, Bs, 0, bhiR, 0);
  STAGE(gA, As, 0, ahiR, 0);
  STAGE(gA, As, 1, aloR, 1);
  VMC0;
  BAR;

  // ---- main loop: 4 quadrant-phases per K-tile ----
  // S123: stage B-lo/B-hi/A-hi of kt+1; S4: stage A-lo of kt+2; TAIL: drain.
#define GROUP(kt, S123, S4, TAIL)                                              \
  do {                                                                         \
    const int s = (kt)&1, o = s ^ 1;                                           \
    short8 aL[4][2], aH[4][2], bL[2][2], bH[2][2];                             \
    /* ---- g1: q00 (mi0-3 x ni0-1) ---- */                                    \
    if (TAIL) { VMC0; } else { VMC4; }                                         \
    _Pragma("unroll") for (int mi = 0; mi < 4; ++mi) {                         \
      aL[mi][0] = AFRAG(s, mi, 0); aL[mi][1] = AFRAG(s, mi, 1);                \
    }                                                                          \
    _Pragma("unroll") for (int ni = 0; ni < 2; ++ni) {                         \
      bL[ni][0] = BFRAG(s, ni, 0); bL[ni][1] = BFRAG(s, ni, 1);                \
    }                                                                          \
    if (S123) STAGE(gB, Bs, o, bloR, (kt) + 1);                                \
    BAR;                                                                       \
    __builtin_amdgcn_s_setprio(1);                                             \
    _Pragma("unroll") for (int mi = 0; mi < 4; ++mi)                           \
      _Pragma("unroll") for (int ni = 0; ni < 2; ++ni)                         \
        _Pragma("unroll") for (int kk = 0; kk < 2; ++kk)                       \
          acc[mi][ni] = mfma16(aL[mi][kk], bL[ni][kk], acc[mi][ni]);           \
    __builtin_amdgcn_s_setprio(0);                                             \
    /* ---- g2: q01 (mi0-3 x ni2-3) ---- */                                    \
    if (!(TAIL)) VMC4;                                                         \
    _Pragma("unroll") for (int ni = 0; ni < 2; ++ni) {                         \
      bH[ni][0] = BFRAG(s, ni + 2, 0); bH[ni][1] = BFRAG(s, ni + 2, 1);        \
    }                                                                          \
    if (S123) STAGE(gB, Bs, o, bhiR, (kt) + 1);                                \
    BAR;                                                                       \
    __builtin_amdgcn_s_setprio(1);                                             \
    _Pragma("unroll") for (int mi = 0; mi < 4; ++mi)                           \
      _Pragma("unroll") for (int ni = 0; ni < 2; ++ni)                         \
        _Pragma("unroll") for (int kk = 0; kk < 2; ++kk)                       \
          acc[mi][ni + 2] = mfma16(aL[mi][kk], bH[ni][kk], acc[mi][ni + 2]);   \
    __builtin_amdgcn_s_setprio(0);                                             \
    /* ---- g3: q10 (mi4-7 x ni0-1) ---- */                                    \
    if (!(TAIL)) VMC4;                                                         \
    _Pragma("unroll") for (int mi = 0; mi < 4; ++mi) {                         \
      aH[mi][0] = AFRAG(s, mi + 4, 0); aH[mi][1] = AFRAG(s, mi + 4, 1);        \
    }                                                                          \
    if (S123) STAGE(gA, As, o, ahiR, (kt) + 1);                                \
    BAR;                                                                       \
    __builtin_amdgcn_s_setprio(1);                                             \
    _Pragma("unroll") for (int mi = 0; mi < 4; ++mi)                           \
      _Pragma("unroll") for (int ni = 0; ni < 2; ++ni)                         \
        _Pragma("unroll") for (int kk = 0; kk < 2; ++kk)                       \
          acc[mi + 4][ni] = mfma16(aH[mi][kk], bL[ni][kk], acc[mi + 4][ni]);   \
    __builtin_amdgcn_s_setprio(0);                                             \
    /* ---- g4: q11 (mi4-7 x ni2-3), no reads ---- */                          \
    if (!(TAIL)) VMC4;                                                         \
    if (S4) STAGE(gA, As, s, aloR, (kt) + 2);                                  \
    BAR;                                                                       \
    __builtin_amdgcn_s_setprio(1);                                             \
    _Pragma("unroll") for (int mi = 0; mi < 4; ++mi)                           \
      _Pragma("unroll") for (int ni = 0; ni < 2; ++ni)                         \
        _Pragma("unroll") for (int kk = 0; kk < 2; ++kk)                       \
          acc[mi + 4][ni + 2] =                                                \
              mfma16(aH[mi][kk], bH[ni][kk], acc[mi + 4][ni + 2]);             \
    __builtin_amdgcn_s_setprio(0);                                             \
    BAR;                                                                       \
  } while (0)

  for (int kt = 0; kt < NT - 2; ++kt) GROUP(kt, 1, 1, 0);
  GROUP(NT - 2, 1, 0, 0);   // kt=62: no A-lo(64) stage
  GROUP(NT - 1, 0, 0, 1);   // kt=63: tail, full drain once, no stages

  // ---- epilogue: C/D layout col=lane&15, row=(lane>>4)*4+reg ----
  float sc = *scale_p;
  int rowbase = bm * BM + wr * 128 + (lane >> 4) * 4;
  int colbase = bn * BN + wc * 64 + (lane & 15);
#pragma unroll
  for (int ni = 0; ni < 4; ++ni) {
    int col = colbase + ni * 16;
    float bv = bias[col];
#pragma unroll
    for (int mi = 0; mi < 8; ++mi) {
#pragma unroll
      for (int r = 0; r < 4; ++r) {
        int row = rowbase + mi * 16 + r;
        C[(size_t)row * N_DIM + col] = sc * acc[mi][ni][r] + bv;
      }
    }
  }
}

// correctness fallback if ws too small (slow, should not normally run)
__global__ __launch_bounds__(256) void naive_kernel(
    const float* __restrict__ x, const int* __restrict__ q,
    const float* __restrict__ sp, const float* __restrict__ zpp,
    const float* __restrict__ bias, float* __restrict__ out) {
  float s = *sp, zp = *zpp;
  size_t total = (size_t)M_DIM * N_DIM;
  size_t stride = (size_t)gridDim.x * blockDim.x;
  for (size_t t = (size_t)blockIdx.x * blockDim.x + threadIdx.x; t < total;
       t += stride) {
    size_t m = t / N_DIM, n = t % N_DIM;
    const float* xr = x + m * K_DIM;
    const int* qr = q + n * K_DIM;
    float acc = 0.f;
    for (int k = 0; k < K_DIM; ++k) acc += xr[k] * ((float)qr[k] - zp);
    out[t] = s * acc + bias[n];
  }
}

extern "C" void kernel_launch(void* const* d_in, const int* in_sizes, int n_in,
                              void* d_out, int out_size, void* d_ws,
                              size_t ws_size, hipStream_t stream) {
  const float* x = (const float*)d_in[0];
  const int* qw = (const int*)d_in[1];
  const float* scale = (const float*)d_in[2];
  const float* zp = (const float*)d_in[3];
  const float* bias = (const float*)d_in[4];
  float* out = (float*)d_out;

  const size_t needW = (size_t)N_DIM * K_DIM * sizeof(unsigned short);  // 128 MiB
  const size_t needX = (size_t)M_DIM * K_DIM * sizeof(unsigned short);  //  64 MiB

  if (ws_size >= needW + needX) {
    unsigned short* wb = (unsigned short*)d_ws;
    unsigned short* xb = (unsigned short*)((char*)d_ws + needW);
    convert_w_kernel<<<(unsigned)((size_t)N_DIM * K_DIM / 2048), 256, 0, stream>>>(qw, zp, wb);
    convert_x_kernel<<<(unsigned)((size_t)M_DIM * K_DIM / 2048), 256, 0, stream>>>(x, xb);
    gemm_bt_kernel<<<(M_DIM / BM) * (N_DIM / BN), 512, 0, stream>>>(xb, wb, out, scale, bias);
  } else {
    naive_kernel<<<4096, 256, 0, stream>>>(x, qw, scale, zp, bias, out);
  }
}